// Round 14
// baseline (4559.354 us; speedup 1.0000x reference)
//
#include <hip/hip_runtime.h>
#include <math.h>

#define BB 64   // batch
#define TT 64   // time steps
#define NN 512  // nodes
#define HH 32   // hidden
#define CC 33   // C_IN + H
#define EE 10   // embed dim
#define GG 128  // 4*H
#define COLS 2112
#define AZS (NN * COLS)    // fallback az slice stride
#define AZS2 (NN * 2048)   // persistent az slice stride
#define KS 4               // fallback split-K
#define KS2 8              // persistent split-K
#define NB 512

// 8-byte coherent (cross-XCD) access via relaxed agent-scope atomics (LLC point).
union DU { double d; float f[2]; };
__device__ __forceinline__ float2 cload8(const float* p) {
  DU u;
  u.d = __hip_atomic_load((const double*)p, __ATOMIC_RELAXED, __HIP_MEMORY_SCOPE_AGENT);
  return make_float2(u.f[0], u.f[1]);
}
__device__ __forceinline__ void cstore8(float* p, float a, float b) {
  DU u; u.f[0] = a; u.f[1] = b;
  __hip_atomic_store((double*)p, u.d, __ATOMIC_RELAXED, __HIP_MEMORY_SCOPE_AGENT);
}

// Hierarchical grid barrier (R13-proven): 8 group counters + release flag.
__device__ __forceinline__ void gbar(unsigned* bar, unsigned epoch, int bid) {
  __syncthreads();
  if (threadIdx.x == 0) {
    unsigned g = (unsigned)bid >> 6;
    __hip_atomic_fetch_add(&bar[g * 32], 1u, __ATOMIC_RELAXED,
                           __HIP_MEMORY_SCOPE_AGENT);
    if (bid == 0) {
      for (int gg = 0; gg < 8; ++gg)
        while (__hip_atomic_load(&bar[gg * 32], __ATOMIC_RELAXED,
                                 __HIP_MEMORY_SCOPE_AGENT) < 64u * epoch)
          __builtin_amdgcn_s_sleep(4);
      __hip_atomic_store(&bar[256], epoch, __ATOMIC_RELAXED,
                         __HIP_MEMORY_SCOPE_AGENT);
    } else {
      while (__hip_atomic_load(&bar[256], __ATOMIC_RELAXED,
                               __HIP_MEMORY_SCOPE_AGENT) < epoch)
        __builtin_amdgcn_s_sleep(4);
    }
  }
  __syncthreads();
}

// ---------------- prologue kernels ----------------

__global__ __launch_bounds__(256) void k_A(const float* __restrict__ E,
                                           const float* __restrict__ mask,
                                           float* __restrict__ A) {
  __shared__ float sE[NN * EE];
  __shared__ float red[256];
  int tid = threadIdx.x, n = blockIdx.x;
  for (int i = tid; i < NN * EE; i += 256) sE[i] = E[i];
  __syncthreads();
  float en[EE];
#pragma unroll
  for (int d = 0; d < EE; ++d) en[d] = sE[n * EE + d];
  float sv[2];
  float mx = -1e30f;
#pragma unroll
  for (int r = 0; r < 2; ++r) {
    int m = tid + r * 256;
    float s = 0.f;
#pragma unroll
    for (int d = 0; d < EE; ++d) s += en[d] * sE[m * EE + d];
    s = fmaxf(s, 0.f);
    sv[r] = s;
    mx = fmaxf(mx, s);
  }
  red[tid] = mx; __syncthreads();
  for (int s = 128; s > 0; s >>= 1) {
    if (tid < s) red[tid] = fmaxf(red[tid], red[tid + s]);
    __syncthreads();
  }
  mx = red[0]; __syncthreads();
  float sum = 0.f;
#pragma unroll
  for (int r = 0; r < 2; ++r) { sv[r] = expf(sv[r] - mx); sum += sv[r]; }
  red[tid] = sum; __syncthreads();
  for (int s = 128; s > 0; s >>= 1) {
    if (tid < s) red[tid] += red[tid + s];
    __syncthreads();
  }
  float inv = 1.f / red[0];
#pragma unroll
  for (int r = 0; r < 2; ++r) {
    int m = tid + r * 256;
    A[n * NN + m] = sv[r] * inv * mask[n * NN + m];
  }
}

// W (classic layout, fallback) + Wp2[n][r][hh][gate] (persistent) + bias
__global__ __launch_bounds__(256) void k_Wb(const float* __restrict__ E,
                                            const float* __restrict__ Wp,
                                            const float* __restrict__ bp,
                                            float* __restrict__ W,
                                            float* __restrict__ Wp2,
                                            float* __restrict__ bias) {
  int tid = threadIdx.x, n = blockIdx.x;
  float e[EE];
#pragma unroll
  for (int d = 0; d < EE; ++d) e[d] = E[n * EE + d];
  for (int i = tid; i < 2 * CC * GG; i += 256) {
    float acc = 0.f;
#pragma unroll
    for (int d = 0; d < EE; ++d) acc += e[d] * Wp[d * (2 * CC * GG) + i];
    W[n * (2 * CC * GG) + i] = acc;
    int r = i >> 7, o = i & 127, g = o >> 5, hh = o & 31;
    Wp2[(size_t)n * 8448 + r * 128 + hh * 4 + g] = acc;
  }
  if (tid < GG) {
    float acc = 0.f;
#pragma unroll
    for (int d = 0; d < EE; ++d) acc += e[d] * bp[d * GG + tid];
    bias[n * GG + tid] = acc;
  }
}

__global__ __launch_bounds__(256) void k_xt(const float* __restrict__ x,
                                            float* __restrict__ xt) {
  __shared__ float tile[64][65];
  int tid = threadIdx.x;
  int t = blockIdx.x >> 3, m0 = (blockIdx.x & 7) << 6;
  int l16 = tid & 15, grp = tid >> 4;
#pragma unroll
  for (int r = 0; r < 4; ++r) {
    int b = r * 16 + grp;
    float4 v = *reinterpret_cast<const float4*>(&x[(b * TT + t) * NN + m0 + l16 * 4]);
    tile[b][l16 * 4 + 0] = v.x; tile[b][l16 * 4 + 1] = v.y;
    tile[b][l16 * 4 + 2] = v.z; tile[b][l16 * 4 + 3] = v.w;
  }
  __syncthreads();
#pragma unroll
  for (int r = 0; r < 4; ++r) {
    int m = r * 16 + grp;
    float4 v;
    v.x = tile[l16 * 4 + 0][m]; v.y = tile[l16 * 4 + 1][m];
    v.z = tile[l16 * 4 + 2][m]; v.w = tile[l16 * 4 + 3][m];
    *reinterpret_cast<float4*>(&xt[(t * NN + m0 + m) * BB + l16 * 4]) = v;
  }
}

// ax[t][n][b] = sum_m A[n][m] * xt[t][m][b]
__global__ __launch_bounds__(256) void k_ax(const float* __restrict__ A,
                                            const float* __restrict__ xt,
                                            float* __restrict__ ax) {
  __shared__ float As[32][68];
  __shared__ float Bs[32][64];
  int tid = threadIdx.x;
  int t = blockIdx.x;
  int n0 = blockIdx.y * 64;
  int tx = tid & 15, ty = tid >> 4;
  int arow = tid >> 2, akc = (tid & 3) * 4;
  int bcol4 = tid & 15, brow0 = tid >> 4;
  float acc[4][4] = {};
  for (int k0 = 0; k0 < NN; k0 += 32) {
    float4 a0 = *reinterpret_cast<const float4*>(&A[(n0 + arow) * NN + k0 + akc]);
    float4 a1 = *reinterpret_cast<const float4*>(&A[(n0 + arow) * NN + k0 + 16 + akc]);
    As[akc + 0][arow] = a0.x; As[akc + 1][arow] = a0.y;
    As[akc + 2][arow] = a0.z; As[akc + 3][arow] = a0.w;
    As[16 + akc + 0][arow] = a1.x; As[16 + akc + 1][arow] = a1.y;
    As[16 + akc + 2][arow] = a1.z; As[16 + akc + 3][arow] = a1.w;
#pragma unroll
    for (int p = 0; p < 2; ++p) {
      int brow = brow0 + p * 16;
      float4 b4 = *reinterpret_cast<const float4*>(&xt[(t * NN + k0 + brow) * BB + bcol4 * 4]);
      *reinterpret_cast<float4*>(&Bs[brow][bcol4 * 4]) = b4;
    }
    __syncthreads();
#pragma unroll
    for (int kk = 0; kk < 32; ++kk) {
      float4 av = *reinterpret_cast<const float4*>(&As[kk][ty * 4]);
      float4 bv = *reinterpret_cast<const float4*>(&Bs[kk][tx * 4]);
      float a[4] = {av.x, av.y, av.z, av.w};
      float b[4] = {bv.x, bv.y, bv.z, bv.w};
#pragma unroll
      for (int i = 0; i < 4; ++i)
#pragma unroll
        for (int j = 0; j < 4; ++j) acc[i][j] += a[i] * b[j];
    }
    __syncthreads();
  }
#pragma unroll
  for (int i = 0; i < 4; ++i) {
    float4 v = {acc[i][0], acc[i][1], acc[i][2], acc[i][3]};
    *reinterpret_cast<float4*>(&ax[(size_t)(t * NN + n0 + ty * 4 + i) * BB + tx * 4]) = v;
  }
}

__global__ __launch_bounds__(256) void k_init(const float* __restrict__ init,
                                              float* __restrict__ h,
                                              float* __restrict__ c,
                                              unsigned* __restrict__ bar) {
  int i = blockIdx.x * 256 + threadIdx.x;
  if (i < 257)
    __hip_atomic_store(&bar[i], 0u, __ATOMIC_RELAXED, __HIP_MEMORY_SCOPE_AGENT);
  if (i >= NN * BB * HH) return;
  int n = i >> 11, r = i & 2047, b = r >> 5, hh = r & 31;
  h[i] = init[((b * 2 + 0) * NN + n) * HH + hh];
  c[i] = init[((b * 2 + 1) * NN + n) * HH + hh];
}

// ---------------- fallback per-step kernels (round-8, proven) ----------------

__global__ __launch_bounds__(256) void k_gemm(const float* __restrict__ A,
                                              const float* __restrict__ h,
                                              const float* __restrict__ xt,
                                              float* __restrict__ azp,
                                              int t, int ks) {
  __shared__ float As[32][68];
  __shared__ float Bs[32][64];
  int tid = threadIdx.x;
  int j0 = blockIdx.x * 64;
  int n0 = blockIdx.y * 64;
  int kz = blockIdx.z;
  int Klen = NN / ks;
  int kbase = kz * Klen;
  int tx = tid & 15, ty = tid >> 4;
  int arow = tid >> 2;
  int akc = (tid & 3) * 4;
  int bcol4 = tid & 15;
  int brow0 = tid >> 4;
  const bool xtile = (j0 >= BB * HH);
  float acc[4][4] = {};
  for (int k0 = kbase; k0 < kbase + Klen; k0 += 32) {
    float4 a0 = *reinterpret_cast<const float4*>(&A[(n0 + arow) * NN + k0 + akc]);
    float4 a1 = *reinterpret_cast<const float4*>(&A[(n0 + arow) * NN + k0 + 16 + akc]);
    As[akc + 0][arow] = a0.x; As[akc + 1][arow] = a0.y;
    As[akc + 2][arow] = a0.z; As[akc + 3][arow] = a0.w;
    As[16 + akc + 0][arow] = a1.x; As[16 + akc + 1][arow] = a1.y;
    As[16 + akc + 2][arow] = a1.z; As[16 + akc + 3][arow] = a1.w;
#pragma unroll
    for (int p = 0; p < 2; ++p) {
      int brow = brow0 + p * 16;
      float4 b4;
      if (!xtile)
        b4 = *reinterpret_cast<const float4*>(&h[(k0 + brow) * (BB * HH) + j0 + bcol4 * 4]);
      else
        b4 = *reinterpret_cast<const float4*>(&xt[(t * NN + k0 + brow) * BB + (j0 - BB * HH) + bcol4 * 4]);
      *reinterpret_cast<float4*>(&Bs[brow][bcol4 * 4]) = b4;
    }
    __syncthreads();
#pragma unroll
    for (int kk = 0; kk < 32; ++kk) {
      float4 av = *reinterpret_cast<const float4*>(&As[kk][ty * 4]);
      float4 bv = *reinterpret_cast<const float4*>(&Bs[kk][tx * 4]);
      float a[4] = {av.x, av.y, av.z, av.w};
      float b[4] = {bv.x, bv.y, bv.z, bv.w};
#pragma unroll
      for (int i = 0; i < 4; ++i)
#pragma unroll
        for (int j = 0; j < 4; ++j) acc[i][j] += a[i] * b[j];
    }
    __syncthreads();
  }
  float* dst = azp + (size_t)kz * AZS;
#pragma unroll
  for (int i = 0; i < 4; ++i) {
    float4 v = {acc[i][0], acc[i][1], acc[i][2], acc[i][3]};
    *reinterpret_cast<float4*>(&dst[(n0 + ty * 4 + i) * COLS + j0 + tx * 4]) = v;
  }
}

__global__ __launch_bounds__(256) void k_step(const float* __restrict__ xt,
                                              const float* __restrict__ W,
                                              const float* __restrict__ bias,
                                              const float* __restrict__ azp,
                                              float* __restrict__ h,
                                              float* __restrict__ c,
                                              float* __restrict__ out,
                                              int t, int ks) {
  __shared__ float Wl[2 * CC * GG];
  __shared__ float zl[2 * CC * 68];
  int tid = threadIdx.x, n = blockIdx.x;
  const float4* Wg = reinterpret_cast<const float4*>(&W[n * (2 * CC * GG)]);
  for (int i = tid; i < (2 * CC * GG) / 4; i += 256)
    *reinterpret_cast<float4*>(&Wl[i * 4]) = Wg[i];
  for (int i = tid; i < BB * HH; i += 256) {
    int b = i >> 5, hh = i & 31;
    zl[(1 + hh) * 68 + b] = h[n * (BB * HH) + i];
    float s = azp[n * COLS + i];
    for (int kz = 1; kz < ks; ++kz) s += azp[(size_t)kz * AZS + n * COLS + i];
    zl[(CC + 1 + hh) * 68 + b] = s;
  }
  if (tid < BB) {
    zl[0 * 68 + tid] = xt[(t * NN + n) * BB + tid];
    float s = azp[n * COLS + BB * HH + tid];
    for (int kz = 1; kz < ks; ++kz) s += azp[(size_t)kz * AZS + n * COLS + BB * HH + tid];
    zl[CC * 68 + tid] = s;
  }
  __syncthreads();
  int tx = tid & 31, tyb = tid >> 5;
  float acc[8][4];
  {
    float4 bv = *reinterpret_cast<const float4*>(&bias[n * GG + tx * 4]);
#pragma unroll
    for (int bb = 0; bb < 8; ++bb) {
      acc[bb][0] = bv.x; acc[bb][1] = bv.y; acc[bb][2] = bv.z; acc[bb][3] = bv.w;
    }
  }
  for (int k = 0; k < 2; ++k) {
    for (int cc = 0; cc < CC; ++cc) {
      float4 w4 = *reinterpret_cast<const float4*>(&Wl[(k * CC + cc) * GG + tx * 4]);
      float4 za = *reinterpret_cast<const float4*>(&zl[(k * CC + cc) * 68 + tyb * 8]);
      float4 zb = *reinterpret_cast<const float4*>(&zl[(k * CC + cc) * 68 + tyb * 8 + 4]);
      float zv[8] = {za.x, za.y, za.z, za.w, zb.x, zb.y, zb.z, zb.w};
      float wv[4] = {w4.x, w4.y, w4.z, w4.w};
#pragma unroll
      for (int bb = 0; bb < 8; ++bb)
#pragma unroll
        for (int j = 0; j < 4; ++j) acc[bb][j] += zv[bb] * wv[j];
    }
  }
  __syncthreads();
  float* gl = Wl;
#pragma unroll
  for (int bb = 0; bb < 8; ++bb) {
    float4 v = {acc[bb][0], acc[bb][1], acc[bb][2], acc[bb][3]};
    *reinterpret_cast<float4*>(&gl[(tyb * 8 + bb) * GG + tx * 4]) = v;
  }
  __syncthreads();
  for (int i = tid; i < BB * HH; i += 256) {
    int b = i >> 5, hh = i & 31;
    float gi = gl[b * GG + hh];
    float gf = gl[b * GG + 32 + hh];
    float go = gl[b * GG + 64 + hh];
    float gg = gl[b * GG + 96 + hh];
    float cold = c[n * (BB * HH) + i];
    float si = 1.f / (1.f + expf(-gi));
    float sf = 1.f / (1.f + expf(-gf));
    float so = 1.f / (1.f + expf(-go));
    float cnew = sf * cold + si * tanhf(gg);
    float hnew = so * tanhf(cnew);
    c[n * (BB * HH) + i] = cnew;
    h[n * (BB * HH) + i] = hnew;
    out[((b * TT + t) * NN + n) * HH + hh] = hnew;
  }
}

// ---------------- persistent whole-recurrence kernel ----------------
// 512 blocks x 256 threads, 50.7 KB LDS, 2 blocks/CU.
// Phase A: one fixed 128x128 job/block (KS2=8), A persistent in LDS, 8x8 acc.
// Phase B: node n = bid; gates via Wp2 (4 gates/thread), inline LSTM update.
__global__ __launch_bounds__(256, 2) void k_persist(
    const float* __restrict__ A, float* __restrict__ h,
    const float* __restrict__ xt, const float* __restrict__ ax,
    const float* __restrict__ Wp2, const float* __restrict__ bias,
    float* __restrict__ c, float* __restrict__ azp, float* __restrict__ out,
    unsigned* __restrict__ bar) {
  __shared__ float smem[8192 + 4488];
  float* Asp = smem;          // [64][128] persistent A-slice
  float* Bs  = smem + 8192;   // [32][132] phase-A h tile
  float* zl  = smem + 8192;   // [66][68]  phase-B z rows (alias)
  const int tid = threadIdx.x;
  const int bid = blockIdx.x;
  const int n = bid;
  const int kz = bid & 7;
  const int rem = bid >> 3;
  const int jc = rem & 15, nr = rem >> 4;
  const int n0 = nr * 128, j0 = jc * 128, kbase = kz * 64;
  const int tx2 = tid & 15, ty2 = tid >> 4;
  const int kks = tid >> 3, jg = tid & 7;
  const int hhp = tid & 15, boct = tid >> 4;
  const int hh2 = hhp * 2;

  // stage A-slice once: Asp[k][row] = A[n0+row][kbase+k]
  {
    int row = tid >> 1, half = tid & 1;
#pragma unroll
    for (int p = 0; p < 8; ++p) {
      float4 a = *reinterpret_cast<const float4*>(
          &A[(size_t)(n0 + row) * NN + kbase + half * 32 + p * 4]);
      Asp[(half * 32 + p * 4 + 0) * 128 + row] = a.x;
      Asp[(half * 32 + p * 4 + 1) * 128 + row] = a.y;
      Asp[(half * 32 + p * 4 + 2) * 128 + row] = a.z;
      Asp[(half * 32 + p * 4 + 3) * 128 + row] = a.w;
    }
  }
  float bs2[8];
  if (tid < 128) {
#pragma unroll
    for (int hh = 0; hh < 2; ++hh)
#pragma unroll
      for (int g = 0; g < 4; ++g)
        bs2[hh * 4 + g] = bias[n * GG + g * 32 + hh2 + hh];
  }
  __syncthreads();

  unsigned ep = 1;
  for (int t = 0; t < TT; ++t) {
    // ---------- phase A ----------
    float acc[8][8];
#pragma unroll
    for (int i = 0; i < 8; ++i)
#pragma unroll
      for (int j = 0; j < 8; ++j) acc[i][j] = 0.f;
#pragma unroll 1
    for (int kt = 0; kt < 2; ++kt) {
      {
        const float* hsrc = &h[(size_t)(kbase + kt * 32 + kks) * 2048 + j0 + jg * 16];
        float* bd = &Bs[kks * 132 + jg * 16];
#pragma unroll
        for (int q = 0; q < 4; ++q) {
          float2 u0 = cload8(hsrc + q * 4);
          float2 u1 = cload8(hsrc + q * 4 + 2);
          float4 v = {u0.x, u0.y, u1.x, u1.y};
          *reinterpret_cast<float4*>(&bd[q * 4]) = v;
        }
      }
      __syncthreads();
#pragma unroll 2
      for (int kk = 0; kk < 32; ++kk) {
        const float* ap = &Asp[(kt * 32 + kk) * 128 + ty2 * 8];
        const float* bp = &Bs[kk * 132 + tx2 * 8];
        float4 a0 = *reinterpret_cast<const float4*>(ap);
        float4 a1 = *reinterpret_cast<const float4*>(ap + 4);
        float4 b0 = *reinterpret_cast<const float4*>(bp);
        float4 b1 = *reinterpret_cast<const float4*>(bp + 4);
        float av[8] = {a0.x, a0.y, a0.z, a0.w, a1.x, a1.y, a1.z, a1.w};
        float bv[8] = {b0.x, b0.y, b0.z, b0.w, b1.x, b1.y, b1.z, b1.w};
#pragma unroll
        for (int i = 0; i < 8; ++i)
#pragma unroll
          for (int j = 0; j < 8; ++j) acc[i][j] += av[i] * bv[j];
      }
      __syncthreads();
    }
    {
      float* dst = azp + (size_t)kz * AZS2 + (size_t)(n0 + ty2 * 8) * 2048 + j0 + tx2 * 8;
#pragma unroll
      for (int i = 0; i < 8; ++i)
#pragma unroll
        for (int j2 = 0; j2 < 4; ++j2)
          cstore8(dst + (size_t)i * 2048 + j2 * 2, acc[i][j2 * 2], acc[i][j2 * 2 + 1]);
    }
    gbar(bar, ep, bid); ++ep;

    // ---------- phase B ----------
#pragma unroll 1
    for (int k = 0; k < 4; ++k) {
      int di = tid + k * 256;
      int i = di * 2;
      int b = i >> 5, hh = i & 31;
      float2 uh = cload8(&h[(size_t)n * 2048 + i]);
      zl[(1 + hh) * 68 + b] = uh.x;
      zl[(2 + hh) * 68 + b] = uh.y;
      float s0 = 0.f, s1 = 0.f;
#pragma unroll
      for (int kz2 = 0; kz2 < KS2; ++kz2) {
        float2 ua = cload8(&azp[(size_t)kz2 * AZS2 + (size_t)n * 2048 + i]);
        s0 += ua.x; s1 += ua.y;
      }
      zl[(34 + hh) * 68 + b] = s0;
      zl[(35 + hh) * 68 + b] = s1;
    }
    if (tid < BB) {
      zl[0 * 68 + tid]  = xt[(size_t)(t * NN + n) * BB + tid];
      zl[33 * 68 + tid] = ax[(size_t)(t * NN + n) * BB + tid];
    }
    __syncthreads();
    if (tid < 128) {
      float accB[8][8];
#pragma unroll
      for (int b = 0; b < 8; ++b)
#pragma unroll
        for (int q = 0; q < 8; ++q) accB[b][q] = bs2[q];
      const float* wbase = Wp2 + (size_t)n * 8448 + hh2 * 4;
#pragma unroll 2
      for (int r = 0; r < 66; ++r) {
        float4 za = *reinterpret_cast<const float4*>(&zl[r * 68 + boct * 8]);
        float4 zb = *reinterpret_cast<const float4*>(&zl[r * 68 + boct * 8 + 4]);
        float4 w0 = *reinterpret_cast<const float4*>(&wbase[r * 128]);
        float4 w1 = *reinterpret_cast<const float4*>(&wbase[r * 128 + 4]);
        float zv[8] = {za.x, za.y, za.z, za.w, zb.x, zb.y, zb.z, zb.w};
        float wv[8] = {w0.x, w0.y, w0.z, w0.w, w1.x, w1.y, w1.z, w1.w};
#pragma unroll
        for (int b = 0; b < 8; ++b)
#pragma unroll
          for (int q = 0; q < 8; ++q) accB[b][q] += zv[b] * wv[q];
      }
#pragma unroll
      for (int b = 0; b < 8; ++b) {
        int bg = boct * 8 + b;
        int io = n * 2048 + bg * 32 + hh2;
        float c0 = c[io], c1 = c[io + 1];
        float cn[2], hn[2];
#pragma unroll
        for (int hh = 0; hh < 2; ++hh) {
          float gi = accB[b][hh * 4 + 0];
          float gf = accB[b][hh * 4 + 1];
          float go = accB[b][hh * 4 + 2];
          float gG = accB[b][hh * 4 + 3];
          float si = 1.f / (1.f + expf(-gi));
          float sf = 1.f / (1.f + expf(-gf));
          float so = 1.f / (1.f + expf(-go));
          float cc2 = sf * (hh ? c1 : c0) + si * tanhf(gG);
          cn[hh] = cc2;
          hn[hh] = so * tanhf(cc2);
        }
        c[io] = cn[0]; c[io + 1] = cn[1];
        cstore8(&h[io], hn[0], hn[1]);
        float2 ov = {hn[0], hn[1]};
        *reinterpret_cast<float2*>(&out[((size_t)(bg * TT + t) * NN + n) * HH + hh2]) = ov;
      }
    }
    gbar(bar, ep, bid); ++ep;
  }
}

extern "C" void kernel_launch(void* const* d_in, const int* in_sizes, int n_in,
                              void* d_out, int out_size, void* d_ws, size_t ws_size,
                              hipStream_t stream) {
  const float* x    = (const float*)d_in[0];
  const float* init = (const float*)d_in[1];
  const float* E    = (const float*)d_in[2];
  const float* mask = (const float*)d_in[3];
  const float* Wp   = (const float*)d_in[4];
  const float* bp   = (const float*)d_in[5];
  float* out = (float*)d_out;
  float* ws = (float*)d_ws;
  float* A    = ws;
  float* W    = A + NN * NN;                 // classic layout (fallback)
  float* Wp2  = W + NN * 2 * CC * GG;        // permuted [n][r][hh][g]
  float* bias = Wp2 + NN * 2 * CC * GG;
  float* xt   = bias + NN * GG;
  float* ax   = xt + TT * NN * BB;
  float* h    = ax + TT * NN * BB;
  float* c    = h + NN * BB * HH;
  float* azp  = c + NN * BB * HH;            // KS2 slices of NN*2048
  unsigned* bar = (unsigned*)(azp + (size_t)KS2 * AZS2);

  k_A<<<NN, 256, 0, stream>>>(E, mask, A);
  k_Wb<<<NN, 256, 0, stream>>>(E, Wp, bp, W, Wp2, bias);
  k_xt<<<TT * 8, 256, 0, stream>>>(x, xt);
  k_ax<<<dim3(TT, 8), 256, 0, stream>>>(A, xt, ax);
  k_init<<<(NN * BB * HH + 255) / 256, 256, 0, stream>>>(init, h, c, bar);

  void* args[10] = {(void*)&A, (void*)&h, (void*)&xt, (void*)&ax, (void*)&Wp2,
                    (void*)&bias, (void*)&c, (void*)&azp, (void*)&out, (void*)&bar};
  hipError_t err = hipLaunchCooperativeKernel((const void*)k_persist, dim3(NB),
                                              dim3(256), args, 0, stream);
  if (err != hipSuccess) {
    for (int t = 0; t < TT; ++t) {
      k_gemm<<<dim3(33, 8, KS), 256, 0, stream>>>(A, h, xt, azp, t, KS);
      k_step<<<NN, 256, 0, stream>>>(xt, W, bias, azp, h, c, out, t, KS);
    }
  }
}

// Round 15
// 3724.585 us; speedup vs baseline: 1.2241x; 1.2241x over previous
//
#include <hip/hip_runtime.h>
#include <math.h>

#define BB 64   // batch
#define TT 64   // time steps
#define NN 512  // nodes
#define HH 32   // hidden
#define CC 33   // C_IN + H
#define EE 10   // embed dim
#define GG 128  // 4*H
#define COLS 2112
#define AZS (NN * COLS)    // fallback az slice stride
#define AZS2 (NN * 2048)   // persistent az slice stride
#define KS 4               // split-K (both paths)
#define NB2 256            // persistent blocks
#define THR 512

// Coherent READS: relaxed agent-scope atomics (sc1) -> serviced at LLC (proven R13/14).
union DU { double d; float f[2]; };
__device__ __forceinline__ float2 cload8(const float* p) {
  DU u;
  u.d = __hip_atomic_load((const double*)p, __ATOMIC_RELAXED, __HIP_MEMORY_SCOPE_AGENT);
  return make_float2(u.f[0], u.f[1]);
}

// Writes are NORMAL cached stores; flush local L2 to LLC/HBM before barrier.
__device__ __forceinline__ void flush_l2() {
#if __has_builtin(__builtin_amdgcn_buffer_wbl2)
  __builtin_amdgcn_buffer_wbl2();
#else
  asm volatile("buffer_wbl2" ::: "memory");
#endif
  asm volatile("s_waitcnt vmcnt(0)" ::: "memory");
}

// Hierarchical grid barrier (R13-proven) + L2 writeback on arrival.
__device__ __forceinline__ void gbarW(unsigned* bar, unsigned epoch, int bid) {
  __syncthreads();
  if (threadIdx.x == 0) {
    flush_l2();
    unsigned g = (unsigned)bid >> 5;  // 8 groups of 32 blocks
    __hip_atomic_fetch_add(&bar[g * 32], 1u, __ATOMIC_RELAXED,
                           __HIP_MEMORY_SCOPE_AGENT);
    if (bid == 0) {
      for (int gg = 0; gg < 8; ++gg)
        while (__hip_atomic_load(&bar[gg * 32], __ATOMIC_RELAXED,
                                 __HIP_MEMORY_SCOPE_AGENT) < 32u * epoch)
          __builtin_amdgcn_s_sleep(4);
      __hip_atomic_store(&bar[256], epoch, __ATOMIC_RELAXED,
                         __HIP_MEMORY_SCOPE_AGENT);
    } else {
      while (__hip_atomic_load(&bar[256], __ATOMIC_RELAXED,
                               __HIP_MEMORY_SCOPE_AGENT) < epoch)
        __builtin_amdgcn_s_sleep(4);
    }
  }
  __syncthreads();
}

// ---------------- prologue kernels ----------------

__global__ __launch_bounds__(256) void k_A(const float* __restrict__ E,
                                           const float* __restrict__ mask,
                                           float* __restrict__ A) {
  __shared__ float sE[NN * EE];
  __shared__ float red[256];
  int tid = threadIdx.x, n = blockIdx.x;
  for (int i = tid; i < NN * EE; i += 256) sE[i] = E[i];
  __syncthreads();
  float en[EE];
#pragma unroll
  for (int d = 0; d < EE; ++d) en[d] = sE[n * EE + d];
  float sv[2];
  float mx = -1e30f;
#pragma unroll
  for (int r = 0; r < 2; ++r) {
    int m = tid + r * 256;
    float s = 0.f;
#pragma unroll
    for (int d = 0; d < EE; ++d) s += en[d] * sE[m * EE + d];
    s = fmaxf(s, 0.f);
    sv[r] = s;
    mx = fmaxf(mx, s);
  }
  red[tid] = mx; __syncthreads();
  for (int s = 128; s > 0; s >>= 1) {
    if (tid < s) red[tid] = fmaxf(red[tid], red[tid + s]);
    __syncthreads();
  }
  mx = red[0]; __syncthreads();
  float sum = 0.f;
#pragma unroll
  for (int r = 0; r < 2; ++r) { sv[r] = expf(sv[r] - mx); sum += sv[r]; }
  red[tid] = sum; __syncthreads();
  for (int s = 128; s > 0; s >>= 1) {
    if (tid < s) red[tid] += red[tid + s];
    __syncthreads();
  }
  float inv = 1.f / red[0];
#pragma unroll
  for (int r = 0; r < 2; ++r) {
    int m = tid + r * 256;
    A[n * NN + m] = sv[r] * inv * mask[n * NN + m];
  }
}

// W (classic, fallback) + Wp2[n][r][hh][gate] (persistent) + bias
__global__ __launch_bounds__(256) void k_Wb(const float* __restrict__ E,
                                            const float* __restrict__ Wp,
                                            const float* __restrict__ bp,
                                            float* __restrict__ W,
                                            float* __restrict__ Wp2,
                                            float* __restrict__ bias) {
  int tid = threadIdx.x, n = blockIdx.x;
  float e[EE];
#pragma unroll
  for (int d = 0; d < EE; ++d) e[d] = E[n * EE + d];
  for (int i = tid; i < 2 * CC * GG; i += 256) {
    float acc = 0.f;
#pragma unroll
    for (int d = 0; d < EE; ++d) acc += e[d] * Wp[d * (2 * CC * GG) + i];
    W[n * (2 * CC * GG) + i] = acc;
    int r = i >> 7, o = i & 127, g = o >> 5, hh = o & 31;
    Wp2[(size_t)n * 8448 + r * 128 + hh * 4 + g] = acc;
  }
  if (tid < GG) {
    float acc = 0.f;
#pragma unroll
    for (int d = 0; d < EE; ++d) acc += e[d] * bp[d * GG + tid];
    bias[n * GG + tid] = acc;
  }
}

__global__ __launch_bounds__(256) void k_xt(const float* __restrict__ x,
                                            float* __restrict__ xt) {
  __shared__ float tile[64][65];
  int tid = threadIdx.x;
  int t = blockIdx.x >> 3, m0 = (blockIdx.x & 7) << 6;
  int l16 = tid & 15, grp = tid >> 4;
#pragma unroll
  for (int r = 0; r < 4; ++r) {
    int b = r * 16 + grp;
    float4 v = *reinterpret_cast<const float4*>(&x[(b * TT + t) * NN + m0 + l16 * 4]);
    tile[b][l16 * 4 + 0] = v.x; tile[b][l16 * 4 + 1] = v.y;
    tile[b][l16 * 4 + 2] = v.z; tile[b][l16 * 4 + 3] = v.w;
  }
  __syncthreads();
#pragma unroll
  for (int r = 0; r < 4; ++r) {
    int m = r * 16 + grp;
    float4 v;
    v.x = tile[l16 * 4 + 0][m]; v.y = tile[l16 * 4 + 1][m];
    v.z = tile[l16 * 4 + 2][m]; v.w = tile[l16 * 4 + 3][m];
    *reinterpret_cast<float4*>(&xt[(t * NN + m0 + m) * BB + l16 * 4]) = v;
  }
}

// ax[t][n][b] = sum_m A[n][m] * xt[t][m][b]
__global__ __launch_bounds__(256) void k_ax(const float* __restrict__ A,
                                            const float* __restrict__ xt,
                                            float* __restrict__ ax) {
  __shared__ float As[32][68];
  __shared__ float Bs[32][64];
  int tid = threadIdx.x;
  int t = blockIdx.x;
  int n0 = blockIdx.y * 64;
  int tx = tid & 15, ty = tid >> 4;
  int arow = tid >> 2, akc = (tid & 3) * 4;
  int bcol4 = tid & 15, brow0 = tid >> 4;
  float acc[4][4] = {};
  for (int k0 = 0; k0 < NN; k0 += 32) {
    float4 a0 = *reinterpret_cast<const float4*>(&A[(n0 + arow) * NN + k0 + akc]);
    float4 a1 = *reinterpret_cast<const float4*>(&A[(n0 + arow) * NN + k0 + 16 + akc]);
    As[akc + 0][arow] = a0.x; As[akc + 1][arow] = a0.y;
    As[akc + 2][arow] = a0.z; As[akc + 3][arow] = a0.w;
    As[16 + akc + 0][arow] = a1.x; As[16 + akc + 1][arow] = a1.y;
    As[16 + akc + 2][arow] = a1.z; As[16 + akc + 3][arow] = a1.w;
#pragma unroll
    for (int p = 0; p < 2; ++p) {
      int brow = brow0 + p * 16;
      float4 b4 = *reinterpret_cast<const float4*>(&xt[(t * NN + k0 + brow) * BB + bcol4 * 4]);
      *reinterpret_cast<float4*>(&Bs[brow][bcol4 * 4]) = b4;
    }
    __syncthreads();
#pragma unroll
    for (int kk = 0; kk < 32; ++kk) {
      float4 av = *reinterpret_cast<const float4*>(&As[kk][ty * 4]);
      float4 bv = *reinterpret_cast<const float4*>(&Bs[kk][tx * 4]);
      float a[4] = {av.x, av.y, av.z, av.w};
      float b[4] = {bv.x, bv.y, bv.z, bv.w};
#pragma unroll
      for (int i = 0; i < 4; ++i)
#pragma unroll
        for (int j = 0; j < 4; ++j) acc[i][j] += a[i] * b[j];
    }
    __syncthreads();
  }
#pragma unroll
  for (int i = 0; i < 4; ++i) {
    float4 v = {acc[i][0], acc[i][1], acc[i][2], acc[i][3]};
    *reinterpret_cast<float4*>(&ax[(size_t)(t * NN + n0 + ty * 4 + i) * BB + tx * 4]) = v;
  }
}

__global__ __launch_bounds__(256) void k_init(const float* __restrict__ init,
                                              float* __restrict__ h,
                                              float* __restrict__ c,
                                              unsigned* __restrict__ bar) {
  int i = blockIdx.x * 256 + threadIdx.x;
  if (i < 257)
    __hip_atomic_store(&bar[i], 0u, __ATOMIC_RELAXED, __HIP_MEMORY_SCOPE_AGENT);
  if (i >= NN * BB * HH) return;
  int n = i >> 11, r = i & 2047, b = r >> 5, hh = r & 31;
  h[i] = init[((b * 2 + 0) * NN + n) * HH + hh];
  c[i] = init[((b * 2 + 1) * NN + n) * HH + hh];
}

// ---------------- fallback per-step kernels (round-8, proven) ----------------

__global__ __launch_bounds__(256) void k_gemm(const float* __restrict__ A,
                                              const float* __restrict__ h,
                                              const float* __restrict__ xt,
                                              float* __restrict__ azp,
                                              int t, int ks) {
  __shared__ float As[32][68];
  __shared__ float Bs[32][64];
  int tid = threadIdx.x;
  int j0 = blockIdx.x * 64;
  int n0 = blockIdx.y * 64;
  int kz = blockIdx.z;
  int Klen = NN / ks;
  int kbase = kz * Klen;
  int tx = tid & 15, ty = tid >> 4;
  int arow = tid >> 2;
  int akc = (tid & 3) * 4;
  int bcol4 = tid & 15;
  int brow0 = tid >> 4;
  const bool xtile = (j0 >= BB * HH);
  float acc[4][4] = {};
  for (int k0 = kbase; k0 < kbase + Klen; k0 += 32) {
    float4 a0 = *reinterpret_cast<const float4*>(&A[(n0 + arow) * NN + k0 + akc]);
    float4 a1 = *reinterpret_cast<const float4*>(&A[(n0 + arow) * NN + k0 + 16 + akc]);
    As[akc + 0][arow] = a0.x; As[akc + 1][arow] = a0.y;
    As[akc + 2][arow] = a0.z; As[akc + 3][arow] = a0.w;
    As[16 + akc + 0][arow] = a1.x; As[16 + akc + 1][arow] = a1.y;
    As[16 + akc + 2][arow] = a1.z; As[16 + akc + 3][arow] = a1.w;
#pragma unroll
    for (int p = 0; p < 2; ++p) {
      int brow = brow0 + p * 16;
      float4 b4;
      if (!xtile)
        b4 = *reinterpret_cast<const float4*>(&h[(k0 + brow) * (BB * HH) + j0 + bcol4 * 4]);
      else
        b4 = *reinterpret_cast<const float4*>(&xt[(t * NN + k0 + brow) * BB + (j0 - BB * HH) + bcol4 * 4]);
      *reinterpret_cast<float4*>(&Bs[brow][bcol4 * 4]) = b4;
    }
    __syncthreads();
#pragma unroll
    for (int kk = 0; kk < 32; ++kk) {
      float4 av = *reinterpret_cast<const float4*>(&As[kk][ty * 4]);
      float4 bv = *reinterpret_cast<const float4*>(&Bs[kk][tx * 4]);
      float a[4] = {av.x, av.y, av.z, av.w};
      float b[4] = {bv.x, bv.y, bv.z, bv.w};
#pragma unroll
      for (int i = 0; i < 4; ++i)
#pragma unroll
        for (int j = 0; j < 4; ++j) acc[i][j] += a[i] * b[j];
    }
    __syncthreads();
  }
  float* dst = azp + (size_t)kz * AZS;
#pragma unroll
  for (int i = 0; i < 4; ++i) {
    float4 v = {acc[i][0], acc[i][1], acc[i][2], acc[i][3]};
    *reinterpret_cast<float4*>(&dst[(n0 + ty * 4 + i) * COLS + j0 + tx * 4]) = v;
  }
}

__global__ __launch_bounds__(256) void k_step(const float* __restrict__ xt,
                                              const float* __restrict__ W,
                                              const float* __restrict__ bias,
                                              const float* __restrict__ azp,
                                              float* __restrict__ h,
                                              float* __restrict__ c,
                                              float* __restrict__ out,
                                              int t, int ks) {
  __shared__ float Wl[2 * CC * GG];
  __shared__ float zl[2 * CC * 68];
  int tid = threadIdx.x, n = blockIdx.x;
  const float4* Wg = reinterpret_cast<const float4*>(&W[n * (2 * CC * GG)]);
  for (int i = tid; i < (2 * CC * GG) / 4; i += 256)
    *reinterpret_cast<float4*>(&Wl[i * 4]) = Wg[i];
  for (int i = tid; i < BB * HH; i += 256) {
    int b = i >> 5, hh = i & 31;
    zl[(1 + hh) * 68 + b] = h[n * (BB * HH) + i];
    float s = azp[n * COLS + i];
    for (int kz = 1; kz < ks; ++kz) s += azp[(size_t)kz * AZS + n * COLS + i];
    zl[(CC + 1 + hh) * 68 + b] = s;
  }
  if (tid < BB) {
    zl[0 * 68 + tid] = xt[(t * NN + n) * BB + tid];
    float s = azp[n * COLS + BB * HH + tid];
    for (int kz = 1; kz < ks; ++kz) s += azp[(size_t)kz * AZS + n * COLS + BB * HH + tid];
    zl[CC * 68 + tid] = s;
  }
  __syncthreads();
  int tx = tid & 31, tyb = tid >> 5;
  float acc[8][4];
  {
    float4 bv = *reinterpret_cast<const float4*>(&bias[n * GG + tx * 4]);
#pragma unroll
    for (int bb = 0; bb < 8; ++bb) {
      acc[bb][0] = bv.x; acc[bb][1] = bv.y; acc[bb][2] = bv.z; acc[bb][3] = bv.w;
    }
  }
  for (int k = 0; k < 2; ++k) {
    for (int cc = 0; cc < CC; ++cc) {
      float4 w4 = *reinterpret_cast<const float4*>(&Wl[(k * CC + cc) * GG + tx * 4]);
      float4 za = *reinterpret_cast<const float4*>(&zl[(k * CC + cc) * 68 + tyb * 8]);
      float4 zb = *reinterpret_cast<const float4*>(&zl[(k * CC + cc) * 68 + tyb * 8 + 4]);
      float zv[8] = {za.x, za.y, za.z, za.w, zb.x, zb.y, zb.z, zb.w};
      float wv[4] = {w4.x, w4.y, w4.z, w4.w};
#pragma unroll
      for (int bb = 0; bb < 8; ++bb)
#pragma unroll
        for (int j = 0; j < 4; ++j) acc[bb][j] += zv[bb] * wv[j];
    }
  }
  __syncthreads();
  float* gl = Wl;
#pragma unroll
  for (int bb = 0; bb < 8; ++bb) {
    float4 v = {acc[bb][0], acc[bb][1], acc[bb][2], acc[bb][3]};
    *reinterpret_cast<float4*>(&gl[(tyb * 8 + bb) * GG + tx * 4]) = v;
  }
  __syncthreads();
  for (int i = tid; i < BB * HH; i += 256) {
    int b = i >> 5, hh = i & 31;
    float gi = gl[b * GG + hh];
    float gf = gl[b * GG + 32 + hh];
    float go = gl[b * GG + 64 + hh];
    float gg = gl[b * GG + 96 + hh];
    float cold = c[n * (BB * HH) + i];
    float si = 1.f / (1.f + expf(-gi));
    float sf = 1.f / (1.f + expf(-gf));
    float so = 1.f / (1.f + expf(-go));
    float cnew = sf * cold + si * tanhf(gg);
    float hnew = so * tanhf(cnew);
    c[n * (BB * HH) + i] = cnew;
    h[n * (BB * HH) + i] = hnew;
    out[((b * TT + t) * NN + n) * HH + hh] = hnew;
  }
}

// ---------------- persistent whole-recurrence kernel ----------------
// 256 blocks x 512 threads, 103.5 KB LDS -> 1 block/CU (8 waves).
// Phase A: fixed 128x128 job (KS=4), A in LDS once, 8x4 acc, NORMAL az stores.
// Phase B: 2 nodes/block, gates via Wp2, inline LSTM, NORMAL h/out stores.
// Coherence: cload8 (sc1) reads + buffer_wbl2 flush at each barrier.
__global__ __launch_bounds__(THR, 1) void k_persist(
    const float* __restrict__ A, float* __restrict__ h,
    const float* __restrict__ xt, const float* __restrict__ ax,
    const float* __restrict__ Wp2, const float* __restrict__ bias,
    float* __restrict__ c, float* __restrict__ azp, float* __restrict__ out,
    unsigned* __restrict__ bar) {
  __shared__ float smem[16896 + 8976];  // Asp[128][132] + max(Bs[32][132], zl[2][66][68])
  float* Asp = smem;
  float* Bs  = smem + 16896;
  float* zl  = smem + 16896;
  const int tid = threadIdx.x;
  const int bid = blockIdx.x;
  const int kz = bid & 3;
  const int jc = (bid >> 2) & 15;
  const int nr = bid >> 6;
  const int n0 = nr * 128, j0 = jc * 128, kbase = kz * 128;
  const int tx = tid & 31, ty = tid >> 5;     // phase-A compute: cols tx*4, rows ty*8
  const int skr = tid >> 4, scg = tid & 15;   // phase-A staging
  const int nnb = tid >> 8, t8 = tid & 255;   // phase-B
  const int bhh = t8 & 31, boct = t8 >> 5;

  // ---- stage A-slice once: Asp[k][row] = A[n0+row][kbase+k]
  {
    int row = tid >> 2, q4 = tid & 3;
#pragma unroll
    for (int p = 0; p < 8; ++p) {
      int kk = q4 * 32 + p * 4;
      float4 a = *reinterpret_cast<const float4*>(
          &A[(size_t)(n0 + row) * NN + kbase + kk]);
      Asp[(kk + 0) * 132 + row] = a.x;
      Asp[(kk + 1) * 132 + row] = a.y;
      Asp[(kk + 2) * 132 + row] = a.z;
      Asp[(kk + 3) * 132 + row] = a.w;
    }
  }
  __syncthreads();

  unsigned ep = 1;
  for (int t = 0; t < TT; ++t) {
    // ---------- phase A: az[kz][n0..+127][j0..+127] ----------
    float acc[8][4];
#pragma unroll
    for (int i = 0; i < 8; ++i)
#pragma unroll
      for (int j = 0; j < 4; ++j) acc[i][j] = 0.f;
#pragma unroll 1
    for (int kt = 0; kt < 4; ++kt) {
      {
        const float* hsrc = &h[(size_t)(kbase + kt * 32 + skr) * 2048 + j0 + scg * 8];
        float* bd = &Bs[skr * 132 + scg * 8];
#pragma unroll
        for (int q = 0; q < 4; ++q) {
          float2 u = cload8(hsrc + q * 2);
          bd[q * 2] = u.x; bd[q * 2 + 1] = u.y;
        }
      }
      __syncthreads();
#pragma unroll 4
      for (int kk = 0; kk < 32; ++kk) {
        int k = kt * 32 + kk;
        float4 a0 = *reinterpret_cast<const float4*>(&Asp[k * 132 + ty * 8]);
        float4 a1 = *reinterpret_cast<const float4*>(&Asp[k * 132 + ty * 8 + 4]);
        float4 b4 = *reinterpret_cast<const float4*>(&Bs[kk * 132 + tx * 4]);
        float av[8] = {a0.x, a0.y, a0.z, a0.w, a1.x, a1.y, a1.z, a1.w};
        float bv[4] = {b4.x, b4.y, b4.z, b4.w};
#pragma unroll
        for (int i = 0; i < 8; ++i)
#pragma unroll
          for (int j = 0; j < 4; ++j) acc[i][j] += av[i] * bv[j];
      }
      __syncthreads();
    }
    {
      float* dst = azp + (size_t)kz * AZS2 + (size_t)(n0 + ty * 8) * 2048 + j0 + tx * 4;
#pragma unroll
      for (int i = 0; i < 8; ++i) {
        float4 v = {acc[i][0], acc[i][1], acc[i][2], acc[i][3]};
        *reinterpret_cast<float4*>(dst + (size_t)i * 2048) = v;  // normal store
      }
    }
    gbarW(bar, ep, bid); ++ep;

    // ---------- phase B: nodes 2*bid, 2*bid+1 ----------
#pragma unroll 1
    for (int q = 0; q < 4; ++q) {
      int idx = tid + q * THR;          // 0..2047 pairs
      int nn2 = idx >> 10;
      int ip = (idx & 1023) * 2;
      int n2 = bid * 2 + nn2;
      int b = ip >> 5, hh = ip & 31;
      float2 uh = cload8(&h[(size_t)n2 * 2048 + ip]);
      zl[nn2 * 4488 + (1 + hh) * 68 + b] = uh.x;
      zl[nn2 * 4488 + (2 + hh) * 68 + b] = uh.y;
      float s0 = 0.f, s1 = 0.f;
#pragma unroll
      for (int kz2 = 0; kz2 < KS; ++kz2) {
        float2 ua = cload8(&azp[(size_t)kz2 * AZS2 + (size_t)n2 * 2048 + ip]);
        s0 += ua.x; s1 += ua.y;
      }
      zl[nn2 * 4488 + (34 + hh) * 68 + b] = s0;
      zl[nn2 * 4488 + (35 + hh) * 68 + b] = s1;
    }
    if (tid < 128) {
      int nn2 = tid >> 6, b = tid & 63;
      int n2 = bid * 2 + nn2;
      zl[nn2 * 4488 + 0 * 68 + b]  = xt[(size_t)(t * NN + n2) * BB + b];
      zl[nn2 * 4488 + 33 * 68 + b] = ax[(size_t)(t * NN + n2) * BB + b];
    }
    __syncthreads();
    {
      int n2 = bid * 2 + nnb;
      float accB[8][4];
#pragma unroll
      for (int g = 0; g < 4; ++g) {
        float bv = bias[n2 * GG + g * 32 + bhh];
#pragma unroll
        for (int b8 = 0; b8 < 8; ++b8) accB[b8][g] = bv;
      }
      const float* wb = Wp2 + (size_t)n2 * 8448 + bhh * 4;
      const float* zb2 = &zl[nnb * 4488 + boct * 8];
#pragma unroll 2
      for (int r = 0; r < 66; ++r) {
        float4 w4 = *reinterpret_cast<const float4*>(&wb[r * 128]);
        float4 za = *reinterpret_cast<const float4*>(&zb2[r * 68]);
        float4 zbv = *reinterpret_cast<const float4*>(&zb2[r * 68 + 4]);
        float zv[8] = {za.x, za.y, za.z, za.w, zbv.x, zbv.y, zbv.z, zbv.w};
#pragma unroll
        for (int b8 = 0; b8 < 8; ++b8) {
          accB[b8][0] += zv[b8] * w4.x;
          accB[b8][1] += zv[b8] * w4.y;
          accB[b8][2] += zv[b8] * w4.z;
          accB[b8][3] += zv[b8] * w4.w;
        }
      }
#pragma unroll
      for (int b8 = 0; b8 < 8; ++b8) {
        int bg = boct * 8 + b8;
        int io = n2 * 2048 + bg * 32 + bhh;
        float cold = c[io];
        float si = 1.f / (1.f + expf(-accB[b8][0]));
        float sf = 1.f / (1.f + expf(-accB[b8][1]));
        float so = 1.f / (1.f + expf(-accB[b8][2]));
        float cn = sf * cold + si * tanhf(accB[b8][3]);
        float hn = so * tanhf(cn);
        c[io] = cn;
        h[io] = hn;                     // normal store
        out[((size_t)(bg * TT + t) * NN + n2) * HH + bhh] = hn;
      }
    }
    gbarW(bar, ep, bid); ++ep;
  }
}

extern "C" void kernel_launch(void* const* d_in, const int* in_sizes, int n_in,
                              void* d_out, int out_size, void* d_ws, size_t ws_size,
                              hipStream_t stream) {
  const float* x    = (const float*)d_in[0];
  const float* init = (const float*)d_in[1];
  const float* E    = (const float*)d_in[2];
  const float* mask = (const float*)d_in[3];
  const float* Wp   = (const float*)d_in[4];
  const float* bp   = (const float*)d_in[5];
  float* out = (float*)d_out;
  float* ws = (float*)d_ws;
  float* A    = ws;
  float* W    = A + NN * NN;                 // classic layout (fallback)
  float* Wp2  = W + NN * 2 * CC * GG;        // permuted [n][r][hh][g]
  float* bias = Wp2 + NN * 2 * CC * GG;
  float* xt   = bias + NN * GG;
  float* ax   = xt + TT * NN * BB;
  float* h    = ax + TT * NN * BB;
  float* c    = h + NN * BB * HH;
  float* azp  = c + NN * BB * HH;            // KS slices of NN*2048 (and fallback NN*COLS)
  unsigned* bar = (unsigned*)(azp + (size_t)KS * AZS);  // fallback stride is larger; safe

  k_A<<<NN, 256, 0, stream>>>(E, mask, A);
  k_Wb<<<NN, 256, 0, stream>>>(E, Wp, bp, W, Wp2, bias);
  k_xt<<<TT * 8, 256, 0, stream>>>(x, xt);
  k_ax<<<dim3(TT, 8), 256, 0, stream>>>(A, xt, ax);
  k_init<<<(NN * BB * HH + 255) / 256, 256, 0, stream>>>(init, h, c, bar);

  void* args[10] = {(void*)&A, (void*)&h, (void*)&xt, (void*)&ax, (void*)&Wp2,
                    (void*)&bias, (void*)&c, (void*)&azp, (void*)&out, (void*)&bar};
  hipError_t err = hipLaunchCooperativeKernel((const void*)k_persist, dim3(NB2),
                                              dim3(THR), args, 0, stream);
  if (err != hipSuccess) {
    for (int t = 0; t < TT; ++t) {
      k_gemm<<<dim3(33, 8, KS), 256, 0, stream>>>(A, h, xt, azp, t, KS);
      k_step<<<NN, 256, 0, stream>>>(xt, W, bias, azp, h, c, out, t, KS);
    }
  }
}

// Round 16
// 2813.692 us; speedup vs baseline: 1.6204x; 1.3237x over previous
//
#include <hip/hip_runtime.h>
#include <math.h>

#define BB 64   // batch
#define TT 64   // time steps
#define NN 512  // nodes
#define HH 32   // hidden
#define CC 33   // C_IN + H
#define EE 10   // embed dim
#define GG 128  // 4*H
#define AZS2 (NN * 2048)   // az slice stride
#define KS 4               // split-K

// ---------------- prologue kernels (proven) ----------------

__global__ __launch_bounds__(256) void k_A(const float* __restrict__ E,
                                           const float* __restrict__ mask,
                                           float* __restrict__ A) {
  __shared__ float sE[NN * EE];
  __shared__ float red[256];
  int tid = threadIdx.x, n = blockIdx.x;
  for (int i = tid; i < NN * EE; i += 256) sE[i] = E[i];
  __syncthreads();
  float en[EE];
#pragma unroll
  for (int d = 0; d < EE; ++d) en[d] = sE[n * EE + d];
  float sv[2];
  float mx = -1e30f;
#pragma unroll
  for (int r = 0; r < 2; ++r) {
    int m = tid + r * 256;
    float s = 0.f;
#pragma unroll
    for (int d = 0; d < EE; ++d) s += en[d] * sE[m * EE + d];
    s = fmaxf(s, 0.f);
    sv[r] = s;
    mx = fmaxf(mx, s);
  }
  red[tid] = mx; __syncthreads();
  for (int s = 128; s > 0; s >>= 1) {
    if (tid < s) red[tid] = fmaxf(red[tid], red[tid + s]);
    __syncthreads();
  }
  mx = red[0]; __syncthreads();
  float sum = 0.f;
#pragma unroll
  for (int r = 0; r < 2; ++r) { sv[r] = expf(sv[r] - mx); sum += sv[r]; }
  red[tid] = sum; __syncthreads();
  for (int s = 128; s > 0; s >>= 1) {
    if (tid < s) red[tid] += red[tid + s];
    __syncthreads();
  }
  float inv = 1.f / red[0];
#pragma unroll
  for (int r = 0; r < 2; ++r) {
    int m = tid + r * 256;
    A[n * NN + m] = sv[r] * inv * mask[n * NN + m];
  }
}

// Wp2[n][r][hh*4+g] permuted weights + bias[n][g*32+hh]
__global__ __launch_bounds__(256) void k_Wb(const float* __restrict__ E,
                                            const float* __restrict__ Wp,
                                            const float* __restrict__ bp,
                                            float* __restrict__ Wp2,
                                            float* __restrict__ bias) {
  int tid = threadIdx.x, n = blockIdx.x;
  float e[EE];
#pragma unroll
  for (int d = 0; d < EE; ++d) e[d] = E[n * EE + d];
  for (int i = tid; i < 2 * CC * GG; i += 256) {
    float acc = 0.f;
#pragma unroll
    for (int d = 0; d < EE; ++d) acc += e[d] * Wp[d * (2 * CC * GG) + i];
    int r = i >> 7, o = i & 127, g = o >> 5, hh = o & 31;
    Wp2[(size_t)n * 8448 + r * 128 + hh * 4 + g] = acc;
  }
  if (tid < GG) {
    float acc = 0.f;
#pragma unroll
    for (int d = 0; d < EE; ++d) acc += e[d] * bp[d * GG + tid];
    bias[n * GG + tid] = acc;
  }
}

__global__ __launch_bounds__(256) void k_xt(const float* __restrict__ x,
                                            float* __restrict__ xt) {
  __shared__ float tile[64][65];
  int tid = threadIdx.x;
  int t = blockIdx.x >> 3, m0 = (blockIdx.x & 7) << 6;
  int l16 = tid & 15, grp = tid >> 4;
#pragma unroll
  for (int r = 0; r < 4; ++r) {
    int b = r * 16 + grp;
    float4 v = *reinterpret_cast<const float4*>(&x[(b * TT + t) * NN + m0 + l16 * 4]);
    tile[b][l16 * 4 + 0] = v.x; tile[b][l16 * 4 + 1] = v.y;
    tile[b][l16 * 4 + 2] = v.z; tile[b][l16 * 4 + 3] = v.w;
  }
  __syncthreads();
#pragma unroll
  for (int r = 0; r < 4; ++r) {
    int m = r * 16 + grp;
    float4 v;
    v.x = tile[l16 * 4 + 0][m]; v.y = tile[l16 * 4 + 1][m];
    v.z = tile[l16 * 4 + 2][m]; v.w = tile[l16 * 4 + 3][m];
    *reinterpret_cast<float4*>(&xt[(t * NN + m0 + m) * BB + l16 * 4]) = v;
  }
}

// ax[t][n][b] = sum_m A[n][m] * xt[t][m][b]  (hoisted x-cheb terms)
__global__ __launch_bounds__(256) void k_ax(const float* __restrict__ A,
                                            const float* __restrict__ xt,
                                            float* __restrict__ ax) {
  __shared__ float As[32][68];
  __shared__ float Bs[32][64];
  int tid = threadIdx.x;
  int t = blockIdx.x;
  int n0 = blockIdx.y * 64;
  int tx = tid & 15, ty = tid >> 4;
  int arow = tid >> 2, akc = (tid & 3) * 4;
  int bcol4 = tid & 15, brow0 = tid >> 4;
  float acc[4][4] = {};
  for (int k0 = 0; k0 < NN; k0 += 32) {
    float4 a0 = *reinterpret_cast<const float4*>(&A[(n0 + arow) * NN + k0 + akc]);
    float4 a1 = *reinterpret_cast<const float4*>(&A[(n0 + arow) * NN + k0 + 16 + akc]);
    As[akc + 0][arow] = a0.x; As[akc + 1][arow] = a0.y;
    As[akc + 2][arow] = a0.z; As[akc + 3][arow] = a0.w;
    As[16 + akc + 0][arow] = a1.x; As[16 + akc + 1][arow] = a1.y;
    As[16 + akc + 2][arow] = a1.z; As[16 + akc + 3][arow] = a1.w;
#pragma unroll
    for (int p = 0; p < 2; ++p) {
      int brow = brow0 + p * 16;
      float4 b4 = *reinterpret_cast<const float4*>(&xt[(t * NN + k0 + brow) * BB + bcol4 * 4]);
      *reinterpret_cast<float4*>(&Bs[brow][bcol4 * 4]) = b4;
    }
    __syncthreads();
#pragma unroll
    for (int kk = 0; kk < 32; ++kk) {
      float4 av = *reinterpret_cast<const float4*>(&As[kk][ty * 4]);
      float4 bv = *reinterpret_cast<const float4*>(&Bs[kk][tx * 4]);
      float a[4] = {av.x, av.y, av.z, av.w};
      float b[4] = {bv.x, bv.y, bv.z, bv.w};
#pragma unroll
      for (int i = 0; i < 4; ++i)
#pragma unroll
        for (int j = 0; j < 4; ++j) acc[i][j] += a[i] * b[j];
    }
    __syncthreads();
  }
#pragma unroll
  for (int i = 0; i < 4; ++i) {
    float4 v = {acc[i][0], acc[i][1], acc[i][2], acc[i][3]};
    *reinterpret_cast<float4*>(&ax[(size_t)(t * NN + n0 + ty * 4 + i) * BB + tx * 4]) = v;
  }
}

__global__ __launch_bounds__(256) void k_init(const float* __restrict__ init,
                                              float* __restrict__ h,
                                              float* __restrict__ c) {
  int i = blockIdx.x * 256 + threadIdx.x;
  if (i >= NN * BB * HH) return;
  int n = i >> 11, r = i & 2047, b = r >> 5, hh = r & 31;
  h[i] = init[((b * 2 + 0) * NN + n) * HH + hh];
  c[i] = init[((b * 2 + 1) * NN + n) * HH + hh];
}

// ---------------- per-step kernel 1: split-K GEMM (R15 phase-A body) ----------------
// grid (16 col-tiles, 4 row-tiles, KS) = 256 blocks x 512 thr, 82.5 KB LDS (1/CU).
// az2[kz][n][j] = sum_{k in slice} A[n][k] * h[k][j]; 128x128 tile, 8x4 acc.
__global__ __launch_bounds__(512, 1) void k_gemmP(
    const float* __restrict__ A, const float* __restrict__ h,
    float* __restrict__ az2) {
  __shared__ float Asp[128 * 132];  // [k][row]
  __shared__ float Bs[32 * 132];    // [k][col]
  const int tid = threadIdx.x;
  const int j0 = blockIdx.x * 128;
  const int n0 = blockIdx.y * 128;
  const int kz = blockIdx.z;
  const int kbase = kz * 128;
  const int tx = tid & 31, ty = tid >> 5;    // cols tx*4, rows ty*8
  const int skr = tid >> 4, scg = tid & 15;  // B staging

  // stage A-slice: Asp[k][row] = A[n0+row][kbase+k]
  {
    int row = tid >> 2, q4 = tid & 3;
#pragma unroll
    for (int p = 0; p < 8; ++p) {
      int kk = q4 * 32 + p * 4;
      float4 a = *reinterpret_cast<const float4*>(
          &A[(size_t)(n0 + row) * NN + kbase + kk]);
      Asp[(kk + 0) * 132 + row] = a.x;
      Asp[(kk + 1) * 132 + row] = a.y;
      Asp[(kk + 2) * 132 + row] = a.z;
      Asp[(kk + 3) * 132 + row] = a.w;
    }
  }
  __syncthreads();

  float acc[8][4];
#pragma unroll
  for (int i = 0; i < 8; ++i)
#pragma unroll
    for (int j = 0; j < 4; ++j) acc[i][j] = 0.f;
#pragma unroll 1
  for (int kt = 0; kt < 4; ++kt) {
    {
      const float* hsrc = &h[(size_t)(kbase + kt * 32 + skr) * 2048 + j0 + scg * 8];
      float4 v0 = *reinterpret_cast<const float4*>(hsrc);
      float4 v1 = *reinterpret_cast<const float4*>(hsrc + 4);
      float* bd = &Bs[skr * 132 + scg * 8];
      *reinterpret_cast<float4*>(bd) = v0;
      *reinterpret_cast<float4*>(bd + 4) = v1;
    }
    __syncthreads();
#pragma unroll 4
    for (int kk = 0; kk < 32; ++kk) {
      int k = kt * 32 + kk;
      float4 a0 = *reinterpret_cast<const float4*>(&Asp[k * 132 + ty * 8]);
      float4 a1 = *reinterpret_cast<const float4*>(&Asp[k * 132 + ty * 8 + 4]);
      float4 b4 = *reinterpret_cast<const float4*>(&Bs[kk * 132 + tx * 4]);
      float av[8] = {a0.x, a0.y, a0.z, a0.w, a1.x, a1.y, a1.z, a1.w};
      float bv[4] = {b4.x, b4.y, b4.z, b4.w};
#pragma unroll
      for (int i = 0; i < 8; ++i)
#pragma unroll
        for (int j = 0; j < 4; ++j) acc[i][j] += av[i] * bv[j];
    }
    __syncthreads();
  }
  {
    float* dst = az2 + (size_t)kz * AZS2 + (size_t)(n0 + ty * 8) * 2048 + j0 + tx * 4;
#pragma unroll
    for (int i = 0; i < 8; ++i) {
      float4 v = {acc[i][0], acc[i][1], acc[i][2], acc[i][3]};
      *reinterpret_cast<float4*>(dst + (size_t)i * 2048) = v;
    }
  }
}

// ---------------- per-step kernel 2: gates + LSTM (R15 phase-B body) ----------------
// 512 blocks x 256 thr; n = bid; thread = (hh = tid&31, batch-oct = tid>>5).
__global__ __launch_bounds__(256) void k_stepP(
    const float* __restrict__ xt, const float* __restrict__ ax,
    const float* __restrict__ Wp2, const float* __restrict__ bias,
    const float* __restrict__ az2, float* __restrict__ h,
    float* __restrict__ c, float* __restrict__ out, int t) {
  __shared__ float zl[66 * 68];
  const int tid = threadIdx.x, n = blockIdx.x;
  const int bhh = tid & 31, boct = tid >> 5;

  for (int i = tid; i < BB * HH; i += 256) {
    int b = i >> 5, hh = i & 31;
    zl[(1 + hh) * 68 + b] = h[(size_t)n * 2048 + i];
    float s = az2[(size_t)n * 2048 + i];
#pragma unroll
    for (int kz = 1; kz < KS; ++kz)
      s += az2[(size_t)kz * AZS2 + (size_t)n * 2048 + i];
    zl[(34 + hh) * 68 + b] = s;
  }
  if (tid < BB) {
    zl[0 * 68 + tid]  = xt[(size_t)(t * NN + n) * BB + tid];
    zl[33 * 68 + tid] = ax[(size_t)(t * NN + n) * BB + tid];
  }
  __syncthreads();

  float accB[8][4];
#pragma unroll
  for (int g = 0; g < 4; ++g) {
    float bv = bias[n * GG + g * 32 + bhh];
#pragma unroll
    for (int b8 = 0; b8 < 8; ++b8) accB[b8][g] = bv;
  }
  const float* wb = Wp2 + (size_t)n * 8448 + bhh * 4;
  const float* zb2 = &zl[boct * 8];
#pragma unroll 2
  for (int r = 0; r < 66; ++r) {
    float4 w4 = *reinterpret_cast<const float4*>(&wb[r * 128]);
    float4 za = *reinterpret_cast<const float4*>(&zb2[r * 68]);
    float4 zb = *reinterpret_cast<const float4*>(&zb2[r * 68 + 4]);
    float zv[8] = {za.x, za.y, za.z, za.w, zb.x, zb.y, zb.z, zb.w};
#pragma unroll
    for (int b8 = 0; b8 < 8; ++b8) {
      accB[b8][0] += zv[b8] * w4.x;
      accB[b8][1] += zv[b8] * w4.y;
      accB[b8][2] += zv[b8] * w4.z;
      accB[b8][3] += zv[b8] * w4.w;
    }
  }
#pragma unroll
  for (int b8 = 0; b8 < 8; ++b8) {
    int bg = boct * 8 + b8;
    int io = n * 2048 + bg * 32 + bhh;
    float cold = c[io];
    float si = 1.f / (1.f + expf(-accB[b8][0]));
    float sf = 1.f / (1.f + expf(-accB[b8][1]));
    float so = 1.f / (1.f + expf(-accB[b8][2]));
    float cn = sf * cold + si * tanhf(accB[b8][3]);
    float hn = so * tanhf(cn);
    c[io] = cn;
    h[io] = hn;
    out[((size_t)(bg * TT + t) * NN + n) * HH + bhh] = hn;
  }
}

extern "C" void kernel_launch(void* const* d_in, const int* in_sizes, int n_in,
                              void* d_out, int out_size, void* d_ws, size_t ws_size,
                              hipStream_t stream) {
  const float* x    = (const float*)d_in[0];
  const float* init = (const float*)d_in[1];
  const float* E    = (const float*)d_in[2];
  const float* mask = (const float*)d_in[3];
  const float* Wp   = (const float*)d_in[4];
  const float* bp   = (const float*)d_in[5];
  float* out = (float*)d_out;
  float* ws = (float*)d_ws;
  float* A    = ws;                          // 262144
  float* Wp2  = A + NN * NN;                 // 4325376
  float* bias = Wp2 + NN * 2 * CC * GG;      // 65536
  float* xt   = bias + NN * GG;              // 2097152
  float* ax   = xt + TT * NN * BB;           // 2097152
  float* h    = ax + TT * NN * BB;           // 1048576
  float* c    = h + NN * BB * HH;            // 1048576
  float* az2  = c + NN * BB * HH;            // KS * 1048576

  k_A<<<NN, 256, 0, stream>>>(E, mask, A);
  k_Wb<<<NN, 256, 0, stream>>>(E, Wp, bp, Wp2, bias);
  k_xt<<<TT * 8, 256, 0, stream>>>(x, xt);
  k_ax<<<dim3(TT, 8), 256, 0, stream>>>(A, xt, ax);
  k_init<<<(NN * BB * HH + 255) / 256, 256, 0, stream>>>(init, h, c);

  for (int t = 0; t < TT; ++t) {
    k_gemmP<<<dim3(16, 4, KS), 512, 0, stream>>>(A, h, az2);
    k_stepP<<<NN, 256, 0, stream>>>(xt, ax, Wp2, bias, az2, h, c, out, t);
  }
}

// Round 18
// 2312.427 us; speedup vs baseline: 1.9717x; 1.2168x over previous
//
#include <hip/hip_runtime.h>
#include <math.h>

#define BB 64   // batch
#define TT 64   // time steps
#define NN 512  // nodes
#define HH 32   // hidden
#define CC 33   // C_IN + H
#define EE 10   // embed dim
#define GG 128  // 4*H
#define AZS2 (NN * 2048)   // az slice stride
#define KS 4               // split-K
#define BP 72              // LDS pitch in bf16 elems (144B, 16B-aligned)

typedef __attribute__((ext_vector_type(8))) short short8;
typedef __attribute__((ext_vector_type(4))) float f32x4;

__device__ __forceinline__ unsigned short f2b(float f) {
  unsigned int x = __float_as_uint(f);
  x += 0x7fff + ((x >> 16) & 1);
  return (unsigned short)(x >> 16);
}
__device__ __forceinline__ float b2f(unsigned short u) {
  return __uint_as_float(((unsigned int)u) << 16);
}

// ---------------- prologue kernels ----------------

// A = softmax(relu(E E^T),1)*mask ; fp32 A + bf16 3-way split A1/A2/A3
__global__ __launch_bounds__(256) void k_A(const float* __restrict__ E,
                                           const float* __restrict__ mask,
                                           float* __restrict__ A,
                                           unsigned short* __restrict__ A1,
                                           unsigned short* __restrict__ A2,
                                           unsigned short* __restrict__ A3) {
  __shared__ float sE[NN * EE];
  __shared__ float red[256];
  int tid = threadIdx.x, n = blockIdx.x;
  for (int i = tid; i < NN * EE; i += 256) sE[i] = E[i];
  __syncthreads();
  float en[EE];
#pragma unroll
  for (int d = 0; d < EE; ++d) en[d] = sE[n * EE + d];
  float sv[2];
  float mx = -1e30f;
#pragma unroll
  for (int r = 0; r < 2; ++r) {
    int m = tid + r * 256;
    float s = 0.f;
#pragma unroll
    for (int d = 0; d < EE; ++d) s += en[d] * sE[m * EE + d];
    s = fmaxf(s, 0.f);
    sv[r] = s;
    mx = fmaxf(mx, s);
  }
  red[tid] = mx; __syncthreads();
  for (int s = 128; s > 0; s >>= 1) {
    if (tid < s) red[tid] = fmaxf(red[tid], red[tid + s]);
    __syncthreads();
  }
  mx = red[0]; __syncthreads();
  float sum = 0.f;
#pragma unroll
  for (int r = 0; r < 2; ++r) { sv[r] = expf(sv[r] - mx); sum += sv[r]; }
  red[tid] = sum; __syncthreads();
  for (int s = 128; s > 0; s >>= 1) {
    if (tid < s) red[tid] += red[tid + s];
    __syncthreads();
  }
  float inv = 1.f / red[0];
#pragma unroll
  for (int r = 0; r < 2; ++r) {
    int m = tid + r * 256;
    float a = sv[r] * inv * mask[n * NN + m];
    A[n * NN + m] = a;
    unsigned short u1 = f2b(a);
    float r1 = a - b2f(u1);
    unsigned short u2 = f2b(r1);
    float r2 = r1 - b2f(u2);
    A1[n * NN + m] = u1;
    A2[n * NN + m] = u2;
    A3[n * NN + m] = f2b(r2);
  }
}

// Wp2[n][r][hh*4+g] permuted weights + bias[n][g*32+hh]
__global__ __launch_bounds__(256) void k_Wb(const float* __restrict__ E,
                                            const float* __restrict__ Wp,
                                            const float* __restrict__ bp,
                                            float* __restrict__ Wp2,
                                            float* __restrict__ bias) {
  int tid = threadIdx.x, n = blockIdx.x;
  float e[EE];
#pragma unroll
  for (int d = 0; d < EE; ++d) e[d] = E[n * EE + d];
  for (int i = tid; i < 2 * CC * GG; i += 256) {
    float acc = 0.f;
#pragma unroll
    for (int d = 0; d < EE; ++d) acc += e[d] * Wp[d * (2 * CC * GG) + i];
    int r = i >> 7, o = i & 127, g = o >> 5, hh = o & 31;
    Wp2[(size_t)n * 8448 + r * 128 + hh * 4 + g] = acc;
  }
  if (tid < GG) {
    float acc = 0.f;
#pragma unroll
    for (int d = 0; d < EE; ++d) acc += e[d] * bp[d * GG + tid];
    bias[n * GG + tid] = acc;
  }
}

__global__ __launch_bounds__(256) void k_xt(const float* __restrict__ x,
                                            float* __restrict__ xt) {
  __shared__ float tile[64][65];
  int tid = threadIdx.x;
  int t = blockIdx.x >> 3, m0 = (blockIdx.x & 7) << 6;
  int l16 = tid & 15, grp = tid >> 4;
#pragma unroll
  for (int r = 0; r < 4; ++r) {
    int b = r * 16 + grp;
    float4 v = *reinterpret_cast<const float4*>(&x[(b * TT + t) * NN + m0 + l16 * 4]);
    tile[b][l16 * 4 + 0] = v.x; tile[b][l16 * 4 + 1] = v.y;
    tile[b][l16 * 4 + 2] = v.z; tile[b][l16 * 4 + 3] = v.w;
  }
  __syncthreads();
#pragma unroll
  for (int r = 0; r < 4; ++r) {
    int m = r * 16 + grp;
    float4 v;
    v.x = tile[l16 * 4 + 0][m]; v.y = tile[l16 * 4 + 1][m];
    v.z = tile[l16 * 4 + 2][m]; v.w = tile[l16 * 4 + 3][m];
    *reinterpret_cast<float4*>(&xt[(t * NN + m0 + m) * BB + l16 * 4]) = v;
  }
}

// ax[t][n][b] = sum_m A[n][m] * xt[t][m][b]  (hoisted x-cheb terms, fp32)
__global__ __launch_bounds__(256) void k_ax(const float* __restrict__ A,
                                            const float* __restrict__ xt,
                                            float* __restrict__ ax) {
  __shared__ float As[32][68];
  __shared__ float Bs[32][64];
  int tid = threadIdx.x;
  int t = blockIdx.x;
  int n0 = blockIdx.y * 64;
  int tx = tid & 15, ty = tid >> 4;
  int arow = tid >> 2, akc = (tid & 3) * 4;
  int bcol4 = tid & 15, brow0 = tid >> 4;
  float acc[4][4] = {};
  for (int k0 = 0; k0 < NN; k0 += 32) {
    float4 a0 = *reinterpret_cast<const float4*>(&A[(n0 + arow) * NN + k0 + akc]);
    float4 a1 = *reinterpret_cast<const float4*>(&A[(n0 + arow) * NN + k0 + 16 + akc]);
    As[akc + 0][arow] = a0.x; As[akc + 1][arow] = a0.y;
    As[akc + 2][arow] = a0.z; As[akc + 3][arow] = a0.w;
    As[16 + akc + 0][arow] = a1.x; As[16 + akc + 1][arow] = a1.y;
    As[16 + akc + 2][arow] = a1.z; As[16 + akc + 3][arow] = a1.w;
#pragma unroll
    for (int p = 0; p < 2; ++p) {
      int brow = brow0 + p * 16;
      float4 b4 = *reinterpret_cast<const float4*>(&xt[(t * NN + k0 + brow) * BB + bcol4 * 4]);
      *reinterpret_cast<float4*>(&Bs[brow][bcol4 * 4]) = b4;
    }
    __syncthreads();
#pragma unroll
    for (int kk = 0; kk < 32; ++kk) {
      float4 av = *reinterpret_cast<const float4*>(&As[kk][ty * 4]);
      float4 bv = *reinterpret_cast<const float4*>(&Bs[kk][tx * 4]);
      float a[4] = {av.x, av.y, av.z, av.w};
      float b[4] = {bv.x, bv.y, bv.z, bv.w};
#pragma unroll
      for (int i = 0; i < 4; ++i)
#pragma unroll
        for (int j = 0; j < 4; ++j) acc[i][j] += a[i] * b[j];
    }
    __syncthreads();
  }
#pragma unroll
  for (int i = 0; i < 4; ++i) {
    float4 v = {acc[i][0], acc[i][1], acc[i][2], acc[i][3]};
    *reinterpret_cast<float4*>(&ax[(size_t)(t * NN + n0 + ty * 4 + i) * BB + tx * 4]) = v;
  }
}

__global__ __launch_bounds__(256) void k_init(const float* __restrict__ init,
                                              float* __restrict__ h,
                                              float* __restrict__ c) {
  int i = blockIdx.x * 256 + threadIdx.x;
  if (i >= NN * BB * HH) return;
  int n = i >> 11, r = i & 2047, b = r >> 5, hh = r & 31;
  h[i] = init[((b * 2 + 0) * NN + n) * HH + hh];
  c[i] = init[((b * 2 + 1) * NN + n) * HH + hh];
}

// ---------------- per-step kernel 1: bf16x3 (3-way, 6-product) MFMA GEMM ----------------
// grid (16 j-tiles, 4 n-tiles, KS=4) = 256 blocks x 512 thr, 108 KB LDS (1/CU).
// az2[kz][n][j] = sum_k A[n][k]*h[k][j] with ~fp32 precision:
//   A=A1+A2+A3, H=H1+H2+H3 (bf16 each); products kept: 11,12,21,13,22,31.
__global__ __launch_bounds__(512, 1) void k_gemmM(
    const unsigned short* __restrict__ A1, const unsigned short* __restrict__ A2,
    const unsigned short* __restrict__ A3, const float* __restrict__ h,
    float* __restrict__ az2) {
  __shared__ unsigned short lds[6 * 128 * BP];  // 110,592 B
  unsigned short* As1 = lds;
  unsigned short* As2 = As1 + 128 * BP;
  unsigned short* As3 = As2 + 128 * BP;
  unsigned short* Bs1 = As3 + 128 * BP;
  unsigned short* Bs2 = Bs1 + 128 * BP;
  unsigned short* Bs3 = Bs2 + 128 * BP;
  const int tid = threadIdx.x;
  const int j0 = blockIdx.x * 128;
  const int n0 = blockIdx.y * 128;
  const int kz = blockIdx.z;
  // staging ids
  const int arow = tid >> 2, aseg = tid & 3;      // A: row, 16-k segment
  const int bkp = tid >> 4, bjq = tid & 15;       // B: k-pair, j-lane
  // compute ids
  const int w = tid >> 6, l = tid & 63;
  const int rowbase = (w & 3) * 32, colbase = (w >> 2) * 64;
  const int fr = l & 15, fg = l >> 4;

  f32x4 acc[2][4];
#pragma unroll
  for (int rt = 0; rt < 2; ++rt)
#pragma unroll
    for (int ct = 0; ct < 4; ++ct) acc[rt][ct] = (f32x4){0.f, 0.f, 0.f, 0.f};

#pragma unroll 1
  for (int half = 0; half < 2; ++half) {
    const int kb2 = kz * 128 + half * 64;
    // ---- stage A (pre-split bf16 in global, k-contiguous copy)
    {
      const size_t gb = (size_t)(n0 + arow) * NN + kb2 + aseg * 16;
      unsigned short* d1 = &As1[arow * BP + aseg * 16];
      unsigned short* d2 = &As2[arow * BP + aseg * 16];
      unsigned short* d3 = &As3[arow * BP + aseg * 16];
#pragma unroll
      for (int p = 0; p < 2; ++p) {
        *reinterpret_cast<short8*>(d1 + p * 8) = *reinterpret_cast<const short8*>(&A1[gb + p * 8]);
        *reinterpret_cast<short8*>(d2 + p * 8) = *reinterpret_cast<const short8*>(&A2[gb + p * 8]);
        *reinterpret_cast<short8*>(d3 + p * 8) = *reinterpret_cast<const short8*>(&A3[gb + p * 8]);
      }
    }
    // ---- stage B: read h[k][j] fp32, transpose + 3-way split; j = bjq + 16q
    {
      const float* h0 = &h[(size_t)(kb2 + 2 * bkp) * 2048 + j0 + bjq];
      const float* h1 = h0 + 2048;
#pragma unroll
      for (int q = 0; q < 8; ++q) {
        float v0 = h0[q * 16], v1 = h1[q * 16];
        unsigned short p01 = f2b(v0), p11 = f2b(v1);
        float s0 = v0 - b2f(p01), s1 = v1 - b2f(p11);
        unsigned short p02 = f2b(s0), p12 = f2b(s1);
        unsigned short p03 = f2b(s0 - b2f(p02)), p13 = f2b(s1 - b2f(p12));
        int off = (bjq + 16 * q) * BP + 2 * bkp;
        *reinterpret_cast<unsigned int*>(&Bs1[off]) = (unsigned int)p01 | ((unsigned int)p11 << 16);
        *reinterpret_cast<unsigned int*>(&Bs2[off]) = (unsigned int)p02 | ((unsigned int)p12 << 16);
        *reinterpret_cast<unsigned int*>(&Bs3[off]) = (unsigned int)p03 | ((unsigned int)p13 << 16);
      }
    }
    __syncthreads();
    // ---- MFMA: 2 k-chunks of 32
#pragma unroll
    for (int ks = 0; ks < 2; ++ks) {
      short8 a1f[2], a2f[2], a3f[2], b1f[4], b2f4[4], b3f[4];
#pragma unroll
      for (int rt = 0; rt < 2; ++rt) {
        int off = (rowbase + rt * 16 + fr) * BP + ks * 32 + fg * 8;
        a1f[rt] = *reinterpret_cast<const short8*>(&As1[off]);
        a2f[rt] = *reinterpret_cast<const short8*>(&As2[off]);
        a3f[rt] = *reinterpret_cast<const short8*>(&As3[off]);
      }
#pragma unroll
      for (int ct = 0; ct < 4; ++ct) {
        int off = (colbase + ct * 16 + fr) * BP + ks * 32 + fg * 8;
        b1f[ct] = *reinterpret_cast<const short8*>(&Bs1[off]);
        b2f4[ct] = *reinterpret_cast<const short8*>(&Bs2[off]);
        b3f[ct] = *reinterpret_cast<const short8*>(&Bs3[off]);
      }
#pragma unroll
      for (int rt = 0; rt < 2; ++rt)
#pragma unroll
        for (int ct = 0; ct < 4; ++ct) {
          f32x4 a = acc[rt][ct];
          a = __builtin_amdgcn_mfma_f32_16x16x32_bf16(a1f[rt], b1f[ct], a, 0, 0, 0);
          a = __builtin_amdgcn_mfma_f32_16x16x32_bf16(a1f[rt], b2f4[ct], a, 0, 0, 0);
          a = __builtin_amdgcn_mfma_f32_16x16x32_bf16(a2f[rt], b1f[ct], a, 0, 0, 0);
          a = __builtin_amdgcn_mfma_f32_16x16x32_bf16(a1f[rt], b3f[ct], a, 0, 0, 0);
          a = __builtin_amdgcn_mfma_f32_16x16x32_bf16(a2f[rt], b2f4[ct], a, 0, 0, 0);
          a = __builtin_amdgcn_mfma_f32_16x16x32_bf16(a3f[rt], b1f[ct], a, 0, 0, 0);
          acc[rt][ct] = a;
        }
    }
    __syncthreads();
  }
  // ---- write az2 (C/D map: col = lane&15, row = (lane>>4)*4 + reg) — R17-proven
  float* dst = az2 + (size_t)kz * AZS2;
#pragma unroll
  for (int rt = 0; rt < 2; ++rt)
#pragma unroll
    for (int ct = 0; ct < 4; ++ct)
#pragma unroll
      for (int r = 0; r < 4; ++r)
        dst[(size_t)(n0 + rowbase + rt * 16 + fg * 4 + r) * 2048 +
            j0 + colbase + ct * 16 + fr] = acc[rt][ct][r];
}

// ---------------- per-step kernel 2: gates + LSTM (R16, proven) ----------------
__global__ __launch_bounds__(256) void k_stepP(
    const float* __restrict__ xt, const float* __restrict__ ax,
    const float* __restrict__ Wp2, const float* __restrict__ bias,
    const float* __restrict__ az2, float* __restrict__ h,
    float* __restrict__ c, float* __restrict__ out, int t) {
  __shared__ float zl[66 * 68];
  const int tid = threadIdx.x, n = blockIdx.x;
  const int bhh = tid & 31, boct = tid >> 5;

  for (int i = tid; i < BB * HH; i += 256) {
    int b = i >> 5, hh = i & 31;
    zl[(1 + hh) * 68 + b] = h[(size_t)n * 2048 + i];
    float s = az2[(size_t)n * 2048 + i];
#pragma unroll
    for (int kz = 1; kz < KS; ++kz)
      s += az2[(size_t)kz * AZS2 + (size_t)n * 2048 + i];
    zl[(34 + hh) * 68 + b] = s;
  }
  if (tid < BB) {
    zl[0 * 68 + tid]  = xt[(size_t)(t * NN + n) * BB + tid];
    zl[33 * 68 + tid] = ax[(size_t)(t * NN + n) * BB + tid];
  }
  __syncthreads();

  float accB[8][4];
#pragma unroll
  for (int g = 0; g < 4; ++g) {
    float bv = bias[n * GG + g * 32 + bhh];
#pragma unroll
    for (int b8 = 0; b8 < 8; ++b8) accB[b8][g] = bv;
  }
  const float* wb = Wp2 + (size_t)n * 8448 + bhh * 4;
  const float* zb2 = &zl[boct * 8];
#pragma unroll 2
  for (int r = 0; r < 66; ++r) {
    float4 w4 = *reinterpret_cast<const float4*>(&wb[r * 128]);
    float4 za = *reinterpret_cast<const float4*>(&zb2[r * 68]);
    float4 zb = *reinterpret_cast<const float4*>(&zb2[r * 68 + 4]);
    float zv[8] = {za.x, za.y, za.z, za.w, zb.x, zb.y, zb.z, zb.w};
#pragma unroll
    for (int b8 = 0; b8 < 8; ++b8) {
      accB[b8][0] += zv[b8] * w4.x;
      accB[b8][1] += zv[b8] * w4.y;
      accB[b8][2] += zv[b8] * w4.z;
      accB[b8][3] += zv[b8] * w4.w;
    }
  }
#pragma unroll
  for (int b8 = 0; b8 < 8; ++b8) {
    int bg = boct * 8 + b8;
    int io = n * 2048 + bg * 32 + bhh;
    float cold = c[io];
    float si = 1.f / (1.f + expf(-accB[b8][0]));
    float sf = 1.f / (1.f + expf(-accB[b8][1]));
    float so = 1.f / (1.f + expf(-accB[b8][2]));
    float cn = sf * cold + si * tanhf(accB[b8][3]);
    float hn = so * tanhf(cn);
    c[io] = cn;
    h[io] = hn;
    out[((size_t)(bg * TT + t) * NN + n) * HH + bhh] = hn;
  }
}

extern "C" void kernel_launch(void* const* d_in, const int* in_sizes, int n_in,
                              void* d_out, int out_size, void* d_ws, size_t ws_size,
                              hipStream_t stream) {
  const float* x    = (const float*)d_in[0];
  const float* init = (const float*)d_in[1];
  const float* E    = (const float*)d_in[2];
  const float* mask = (const float*)d_in[3];
  const float* Wp   = (const float*)d_in[4];
  const float* bp   = (const float*)d_in[5];
  float* out = (float*)d_out;
  float* ws = (float*)d_ws;
  float* A    = ws;                                      // NN*NN f32
  unsigned short* A1 = (unsigned short*)(A + NN * NN);   // 3x NN*NN bf16
  unsigned short* A2 = A1 + NN * NN;
  unsigned short* A3 = A2 + NN * NN;
  float* Wp2  = (float*)(A3 + NN * NN);
  float* bias = Wp2 + NN * 2 * CC * GG;
  float* xt   = bias + NN * GG;
  float* ax   = xt + TT * NN * BB;
  float* h    = ax + TT * NN * BB;
  float* c    = h + NN * BB * HH;
  float* az2  = c + NN * BB * HH;                        // KS * NN * 2048

  k_A<<<NN, 256, 0, stream>>>(E, mask, A, A1, A2, A3);
  k_Wb<<<NN, 256, 0, stream>>>(E, Wp, bp, Wp2, bias);
  k_xt<<<TT * 8, 256, 0, stream>>>(x, xt);
  k_ax<<<dim3(TT, 8), 256, 0, stream>>>(A, xt, ax);
  k_init<<<(NN * BB * HH + 255) / 256, 256, 0, stream>>>(init, h, c);

  for (int t = 0; t < TT; ++t) {
    k_gemmM<<<dim3(16, 4, KS), 512, 0, stream>>>(A1, A2, A3, h, az2);
    k_stepP<<<NN, 256, 0, stream>>>(xt, ax, Wp2, bias, az2, h, c, out, t);
  }
}